// Round 17
// baseline (481.608 us; speedup 1.0000x reference)
//
#include <hip/hip_runtime.h>

// SwitchGNN (R17: fused aggregation+GEMM, sort hoisted to pre-pass):
//  out = (1/7) * sum_t [ (segsum_t(x[src]) / max(cnt,1)) @ W_t + 1{cnt>0} b_t ]
// P0 convx_k: x -> bf16 rows (256B each); row NN is an all-zero pad row
// P1 wconv_k: W -> bf16, transposed [t][f][k], XOR-swizzled
// P2 fill_k : per-node 64-slot bucket (val = src|t<<17), XCD-partitioned
// P3 sort_k : one wave/node: ballot counts + popc-rank + ds_permute sort
//             (R13-proven); writes bucket back SORTED BY TYPE (pads = NN)
//             + packed per-type counts (7 bytes in a u64)
// P4 fused_k: 128-node tiles, 512 thr, 8 waves, 64KB LDS (2 blocks/CU).
//             Per type: stage W_t via global_load_lds; each wave gathers its
//             16 nodes' type-t edges (from the sorted bucket) directly into
//             swizzled sA rows; barrier; MFMA; barrier. NO aggb round-trip
//             (deletes 176MB write + 179MB read = 35% of pipeline bytes).
//             All __shfl: wave-uniform bounds, all 64 lanes active.

constexpr int NN = 100000;
constexpr int NT = 7;
constexpr int NE = 250000;
constexpr int DD = 128;
constexpr int NROWS = ((NN + 127) / 128) * 128;   // 100096 padded rows
constexpr int NPART = 8;                          // dst partitions = XCDs
constexpr int PSIZE = (NN + NPART - 1) / NPART;   // 12500 nodes per partition
constexpr int EPB = 1024;                         // edges per fill block
constexpr int NSLAB = (NE + EPB - 1) / EPB;       // 245 slabs

typedef short bf16x8 __attribute__((ext_vector_type(8)));
typedef float f32x4 __attribute__((ext_vector_type(4)));
typedef int   i32x4 __attribute__((ext_vector_type(4)));
typedef float fltx4 __attribute__((ext_vector_type(4)));

__device__ __forceinline__ unsigned pack_bf16x2(float lo, float hi) {
    unsigned a = __float_as_uint(lo), b = __float_as_uint(hi);
    unsigned al = (a + 0x7FFFu + ((a >> 16) & 1u)) >> 16;          // RNE
    unsigned bh = (b + 0x7FFFu + ((b >> 16) & 1u)) & 0xFFFF0000u;
    return al | bh;
}

// ---------------------------------------------------------------- conv x ----
__global__ __launch_bounds__(256) void convx_k(
    const float* __restrict__ x, uint4* __restrict__ xb)
{
    int id = blockIdx.x * 256 + threadIdx.x;
    const fltx4* src = (const fltx4*)x;
    fltx4 v0 = __builtin_nontemporal_load(src + (size_t)id * 2);
    fltx4 v1 = __builtin_nontemporal_load(src + (size_t)id * 2 + 1);
    uint4 o;
    o.x = pack_bf16x2(v0[0], v0[1]);
    o.y = pack_bf16x2(v0[2], v0[3]);
    o.z = pack_bf16x2(v1[0], v1[1]);
    o.w = pack_bf16x2(v1[2], v1[3]);
    xb[id] = o;
}

// ---------------------------------------------------------------- W conv ----
__global__ __launch_bounds__(256) void wconv_k(
    const float* __restrict__ W, char* __restrict__ WTb)
{
    int wid = (blockIdx.x * 256 + threadIdx.x) >> 6;
    int lane = threadIdx.x & 63;
    int t = wid >> 7, f = wid & 127;
    if (t >= NT) return;
    const float* Wt = W + (size_t)t * DD * DD;
    float w0 = Wt[(size_t)(2 * lane) * DD + f];
    float w1 = Wt[(size_t)(2 * lane + 1) * DD + f];
    int gran = (lane >> 2) ^ (f & 7);
    *(unsigned*)(WTb + (size_t)t * 32768 + f * 256 + gran * 16 + (lane & 3) * 4)
        = pack_bf16x2(w0, w1);
}

// ------------------------------------------------------------------ fill ----
__global__ __launch_bounds__(256) void fill_k(
    const int* __restrict__ ei,      // [NT][2][NE]
    int* __restrict__ cntT,          // [NN], zeroed
    int* __restrict__ eslots)        // [NN][64]
{
    int part = blockIdx.x & (NPART - 1);
    int slab = blockIdx.x >> 3;
    int t = blockIdx.y;
    int e0 = slab * EPB + threadIdx.x * 4;
    if (e0 >= NE) return;
    const int* p = ei + (size_t)t * 2 * NE;
    i32x4 s4 = __builtin_nontemporal_load((const i32x4*)(p + e0));
    i32x4 d4 = __builtin_nontemporal_load((const i32x4*)(p + NE + e0));
    int lo = part * PSIZE;
    int hi = lo + PSIZE;
    int tv = t << 17;
    #pragma unroll
    for (int k = 0; k < 4; ++k) {
        int src = s4[k];
        int dst = d4[k];
        if (dst >= lo && dst < hi) {
            int pos = atomicAdd(cntT + dst, 1);
            if (pos < 64) eslots[(size_t)dst * 64 + pos] = src | tv;
        }
    }
}

// ------------------------------------------------------------------ sort ----
// One wave per node. R13-proven ballot+rank+ds_permute type sort; writes the
// bucket back sorted (src only, pads = NN) + packed per-type counts.
__global__ __launch_bounds__(256) void sort_k(
    const int* __restrict__ cntT,    // [NN]
    int* __restrict__ eslots,        // [NN][64], in-place sort
    unsigned long long* __restrict__ cntpack)  // [NN] 7 x 8-bit counts
{
    int n = (blockIdx.x * 256 + threadIdx.x) >> 6;
    int lane = threadIdx.x & 63;
    if (n >= NN) return;

    int total = cntT[n];
    if (total > 64) total = 64;      // P(Poisson(17.5)>64) ~ 1e-19
    int val = (lane < total) ? eslots[(size_t)n * 64 + lane] : 0;
    int mytype = (lane < total) ? ((val >> 17) & 7) : 7;

    unsigned long long bal[8];
    #pragma unroll
    for (int t = 0; t < 8; ++t) bal[t] = __ballot(mytype == t);
    int ct[7];
    unsigned long long pk = 0;
    #pragma unroll
    for (int t = 0; t < 7; ++t) {
        ct[t] = (int)__popcll(bal[t]);
        pk |= (unsigned long long)ct[t] << (8 * t);
    }

    unsigned long long before = 0, mine = bal[7];
    #pragma unroll
    for (int t = 0; t < 7; ++t) {
        before |= (mytype > t) ? bal[t] : 0ull;
        mine = (mytype == t) ? bal[t] : mine;
    }
    int rank = (int)__popcll(before)
             + (int)__popcll(mine & ((1ull << lane) - 1ull));
    int sorted = __builtin_amdgcn_ds_permute(rank << 2, val);   // all lanes active
    int srcv = (lane < total) ? (sorted & 0x1FFFF) : NN;        // pads -> zero row

    eslots[(size_t)n * 64 + lane] = srcv;
    if (lane == 0) cntpack[n] = pk;
}

// ----------------------------------------------------------------- fused ----
// 512 threads = 8 waves; wave w gathers rows w*16..w*16+15 into sA, then
// computes quadrant (wy=w>>1, wx=w&1): rows wy*32..+31, cols wx*64..+63.
__global__ __launch_bounds__(512) void fused_k(
    const char* __restrict__ xb,     // [NN+1][256B] bf16 rows (row NN = zeros)
    const int* __restrict__ eslots,  // [NN][64] sorted srcs (pads = NN)
    const unsigned long long* __restrict__ cntpack,  // [NN]
    const char* __restrict__ WTb,    // [NT][128][256B] swizzled bf16
    const float* __restrict__ bias,  // [NT][DD]
    float* __restrict__ out)         // [NN][DD]
{
    __shared__ char sA[128 * 256];   // 32 KB
    __shared__ char sW[128 * 256];   // 32 KB
    int tid = threadIdx.x;
    int w = tid >> 6, lane = tid & 63;
    int wy = w >> 1, wx = w & 1;
    int n0 = blockIdx.x * 128;

    f32x4 acc[2][4];
    #pragma unroll
    for (int i = 0; i < 2; ++i)
        #pragma unroll
        for (int j = 0; j < 4; ++j) acc[i][j] = (f32x4)0.0f;

    for (int t = 0; t < NT; ++t) {
        __syncthreads();   // prev type's MFMA readers done before restage

        // stage W_t: 32 chunks x 1KB, 4 per wave
        const char* wsrc = WTb + (size_t)t * 32768;
        #pragma unroll
        for (int i = 0; i < 4; ++i) {
            int ch = w * 4 + i;
            __builtin_amdgcn_global_load_lds(
                (const __attribute__((address_space(1))) void*)(wsrc + ch * 1024 + lane * 16),
                (__attribute__((address_space(3))) void*)(sW + ch * 1024), 16, 0, 0);
        }

        // gather phase: 16 rounds, one node per wave-round
        for (int rr = 0; rr < 16; ++rr) {
            int row = w * 16 + rr;               // block-local row 0..127
            int node = n0 + row;
            bool live = (node < NN);
            int nn = live ? node : 0;            // clamped addressing
            unsigned long long cp = live ? cntpack[nn] : 0ull;
            int st = 0;
            for (int u = 0; u < t; ++u) st += (int)((cp >> (8 * u)) & 0xFFull);
            int c = (int)((cp >> (8 * t)) & 0xFFull);   // wave-uniform scalar

            // segment preload: all 64 lanes, clamped in-bounds
            int sidx = st + lane;
            sidx = sidx < 63 ? sidx : 63;
            int seg = eslots[(size_t)nn * 64 + sidx];   // src or pad(NN)

            float a0 = 0.f, a1 = 0.f;
            for (int e = 0; e < c; e += 2) {     // c wave-uniform
                int r0 = __shfl(seg, e);         // all lanes active
                int r1 = __shfl(seg, e + 1);
                int s1 = (e + 1 < c) ? r1 : NN;  // pad -> zero row
                unsigned v0 = *(const unsigned*)(xb + (size_t)r0 * 256 + lane * 4);
                unsigned v1 = *(const unsigned*)(xb + (size_t)s1 * 256 + lane * 4);
                a0 += __uint_as_float(v0 << 16) + __uint_as_float(v1 << 16);
                a1 += __uint_as_float(v0 & 0xFFFF0000u) + __uint_as_float(v1 & 0xFFFF0000u);
            }
            float sc = 1.0f / fmaxf((float)c, 1.0f);    // mean folded pre-GEMM
            int gran = (lane >> 2) ^ (row & 7);
            *(unsigned*)(sA + row * 256 + gran * 16 + (lane & 3) * 4)
                = pack_bf16x2(a0 * sc, a1 * sc);
        }
        __syncthreads();   // sA rows + sW staging complete

        #pragma unroll
        for (int cl = 0; cl < 4; ++cl) {
            int gsel = ((cl * 4 + (lane >> 4)) ^ (lane & 7)) << 4;
            bf16x8 A0 = *(const bf16x8*)(sA + (wy * 32 + (lane & 15)) * 256 + gsel);
            bf16x8 A1 = *(const bf16x8*)(sA + (wy * 32 + 16 + (lane & 15)) * 256 + gsel);
            #pragma unroll
            for (int nj = 0; nj < 4; ++nj) {
                bf16x8 B = *(const bf16x8*)(sW + (wx * 64 + nj * 16 + (lane & 15)) * 256 + gsel);
                acc[0][nj] = __builtin_amdgcn_mfma_f32_16x16x32_bf16(A0, B, acc[0][nj], 0, 0, 0);
                acc[1][nj] = __builtin_amdgcn_mfma_f32_16x16x32_bf16(A1, B, acc[1][nj], 0, 0, 0);
            }
        }
    }

    // epilogue: mean over types + per-type bias where the node has edges
    const float inv7 = 1.0f / (float)NT;
    #pragma unroll
    for (int mi = 0; mi < 2; ++mi) {
        #pragma unroll
        for (int v = 0; v < 4; ++v) {
            int n = n0 + wy * 32 + mi * 16 + (lane >> 4) * 4 + v;
            if (n >= NN) continue;
            unsigned long long cp = cntpack[n];
            float add[4] = {0.f, 0.f, 0.f, 0.f};
            #pragma unroll
            for (int t = 0; t < NT; ++t) {
                if ((cp >> (8 * t)) & 0xFFull) {
                    #pragma unroll
                    for (int nj = 0; nj < 4; ++nj)
                        add[nj] += bias[(size_t)t * DD + wx * 64 + nj * 16 + (lane & 15)];
                }
            }
            #pragma unroll
            for (int nj = 0; nj < 4; ++nj)
                out[(size_t)n * DD + wx * 64 + nj * 16 + (lane & 15)]
                    = inv7 * (acc[mi][nj][v] + add[nj]);
        }
    }
}

// ---------------------------------------------------------------- launch ----
extern "C" void kernel_launch(void* const* d_in, const int* in_sizes, int n_in,
                              void* d_out, int out_size, void* d_ws, size_t ws_size,
                              hipStream_t stream) {
    const float* x  = (const float*)d_in[0];
    const int*   ei = (const int*)d_in[1];
    const float* W  = (const float*)d_in[2];
    const float* b  = (const float*)d_in[3];
    float* out = (float*)d_out;
    char* ws = (char*)d_ws;

    // workspace: ~53 MB total (no aggb)
    size_t off = 0;
    char* xb     = ws + off; off += (size_t)(NN + 1) * 256;            // 25.6 MB
    char* WTb    = ws + off; off += (size_t)NT * 128 * 256;            // 224 KB
    int*  eslots = (int*)(ws + off); off += (size_t)NN * 64 * 4;       // 25.6 MB
    int*  cntT   = (int*)(ws + off); off += (size_t)NN * 4;            // 400 KB
    unsigned long long* cntpack = (unsigned long long*)(ws + off);
    off += (size_t)NN * 8;                                             // 800 KB

    convx_k<<<(NN * DD / 8 + 255) / 256, 256, 0, stream>>>(x, (uint4*)xb);
    hipMemsetAsync(xb + (size_t)NN * 256, 0, 256, stream);   // zero pad row
    wconv_k<<<(NT * 128 + 3) / 4, 256, 0, stream>>>(W, WTb);
    hipMemsetAsync(cntT, 0, (size_t)NN * 4, stream);
    fill_k<<<dim3(NSLAB * NPART, NT), 256, 0, stream>>>(ei, cntT, eslots);
    sort_k<<<(NN * 64 + 255) / 256, 256, 0, stream>>>(cntT, eslots, cntpack);
    fused_k<<<NROWS / 128, 512, 0, stream>>>(xb, eslots, cntpack, WTb, b, out);
}

// Round 18
// 258.964 us; speedup vs baseline: 1.8597x; 1.8597x over previous
//
#include <hip/hip_runtime.h>

// SwitchGNN split pipeline (R18 = R16 + 4-blocks/CU BK=64 gemm):
//  out = (1/7) * sum_t [ (segsum_t(x[src]) / max(cnt,1)) @ W_t + 1{cnt>0} b_t ]
// P0 convx_k: x -> bf16 rows (256B each); row NN is an all-zero pad row
// P1 wconv_k: W -> bf16, transposed [t][f][k], XOR-swizzled
// P2 fill_k : per-node 64-slot bucket (val = src|t<<17), XCD-partitioned
// P3 agg_k  : R16 proven: ballot counts + popc-rank + ds_permute type sort,
//             half-wave TYPE split, b64 gathers, wave-uniform shfl bounds
// P4 gemm_k : 128x128 tile, 512 thr, BK=64 single 32KB buffer -> 4 blocks/CU
//             (vs R10/R16's 2): all 782 blocks co-resident, drain stalls hide
//             in cross-block overlap. Staging addressing = R11's proven
//             half-tile pattern; plain __syncthreads (no asm vmcnt).

constexpr int NN = 100000;
constexpr int NT = 7;
constexpr int NE = 250000;
constexpr int DD = 128;
constexpr int NROWS = ((NN + 127) / 128) * 128;   // 100096 padded rows
constexpr int NPART = 8;                          // dst partitions = XCDs
constexpr int PSIZE = (NN + NPART - 1) / NPART;   // 12500 nodes per partition
constexpr int EPB = 1024;                         // edges per fill block
constexpr int NSLAB = (NE + EPB - 1) / EPB;       // 245 slabs

typedef short bf16x8 __attribute__((ext_vector_type(8)));
typedef float f32x4 __attribute__((ext_vector_type(4)));
typedef int   i32x4 __attribute__((ext_vector_type(4)));
typedef float fltx4 __attribute__((ext_vector_type(4)));

__device__ __forceinline__ unsigned pack_bf16x2(float lo, float hi) {
    unsigned a = __float_as_uint(lo), b = __float_as_uint(hi);
    unsigned al = (a + 0x7FFFu + ((a >> 16) & 1u)) >> 16;          // RNE
    unsigned bh = (b + 0x7FFFu + ((b >> 16) & 1u)) & 0xFFFF0000u;
    return al | bh;
}

// ---------------------------------------------------------------- conv x ----
__global__ __launch_bounds__(256) void convx_k(
    const float* __restrict__ x, uint4* __restrict__ xb)
{
    int id = blockIdx.x * 256 + threadIdx.x;
    const fltx4* src = (const fltx4*)x;
    fltx4 v0 = __builtin_nontemporal_load(src + (size_t)id * 2);
    fltx4 v1 = __builtin_nontemporal_load(src + (size_t)id * 2 + 1);
    uint4 o;
    o.x = pack_bf16x2(v0[0], v0[1]);
    o.y = pack_bf16x2(v0[2], v0[3]);
    o.z = pack_bf16x2(v1[0], v1[1]);
    o.w = pack_bf16x2(v1[2], v1[3]);
    xb[id] = o;
}

// ---------------------------------------------------------------- W conv ----
__global__ __launch_bounds__(256) void wconv_k(
    const float* __restrict__ W, char* __restrict__ WTb)
{
    int wid = (blockIdx.x * 256 + threadIdx.x) >> 6;
    int lane = threadIdx.x & 63;
    int t = wid >> 7, f = wid & 127;
    if (t >= NT) return;
    const float* Wt = W + (size_t)t * DD * DD;
    float w0 = Wt[(size_t)(2 * lane) * DD + f];
    float w1 = Wt[(size_t)(2 * lane + 1) * DD + f];
    int gran = (lane >> 2) ^ (f & 7);
    *(unsigned*)(WTb + (size_t)t * 32768 + f * 256 + gran * 16 + (lane & 3) * 4)
        = pack_bf16x2(w0, w1);
}

// ------------------------------------------------------------------ fill ----
__global__ __launch_bounds__(256) void fill_k(
    const int* __restrict__ ei,      // [NT][2][NE]
    int* __restrict__ cntT,          // [NN], zeroed
    int* __restrict__ eslots)        // [NN][64]
{
    int part = blockIdx.x & (NPART - 1);
    int slab = blockIdx.x >> 3;
    int t = blockIdx.y;
    int e0 = slab * EPB + threadIdx.x * 4;
    if (e0 >= NE) return;
    const int* p = ei + (size_t)t * 2 * NE;
    i32x4 s4 = __builtin_nontemporal_load((const i32x4*)(p + e0));
    i32x4 d4 = __builtin_nontemporal_load((const i32x4*)(p + NE + e0));
    int lo = part * PSIZE;
    int hi = lo + PSIZE;
    int tv = t << 17;
    #pragma unroll
    for (int k = 0; k < 4; ++k) {
        int src = s4[k];
        int dst = d4[k];
        if (dst >= lo && dst < hi) {
            int pos = atomicAdd(cntT + dst, 1);
            if (pos < 64) eslots[(size_t)dst * 64 + pos] = src | tv;
        }
    }
}

// ------------------------------------------------------------- aggregate ----
// R16 proven. One wave per row; ballot counts + popc-rank + ds_permute sort;
// half-wave type split with b64 gathers; all shfls wave-uniform, all lanes.
__global__ __launch_bounds__(256) void agg_k(
    const char* __restrict__ xb,     // [NN+1][256B] bf16 rows (row NN = zeros)
    const int* __restrict__ cntT,    // [NN]
    const int* __restrict__ eslots,  // [NN][64]
    char* __restrict__ aggb,         // [NT][nc][256B], 128-row tiles, swizzled
    unsigned char* __restrict__ bmask, // [NN] per-type has-edges bits
    int c0, int nc)
{
    int wid = (blockIdx.x * 256 + threadIdx.x) >> 6;
    int lane = threadIdx.x & 63;
    if (wid >= nc) return;
    const int n = c0 + wid;
    const bool live = (n < NN);

    int total = live ? cntT[n] : 0;
    if (total > 64) total = 64;      // P(Poisson(17.5)>64) ~ 1e-19
    int val = (live && lane < total)
            ? __builtin_nontemporal_load(eslots + (size_t)n * 64 + lane) : 0;
    int mytype = (lane < total) ? ((val >> 17) & 7) : 7;

    unsigned long long bal[8];
    #pragma unroll
    for (int t = 0; t < 8; ++t) bal[t] = __ballot(mytype == t);
    int ct[7], st[7];
    {
        int s = 0;
        #pragma unroll
        for (int t = 0; t < 7; ++t) { st[t] = s; ct[t] = (int)__popcll(bal[t]); s += ct[t]; }
    }

    unsigned long long before = 0, mine = bal[7];
    #pragma unroll
    for (int t = 0; t < 7; ++t) {
        before |= (mytype > t) ? bal[t] : 0ull;
        mine = (mytype == t) ? bal[t] : mine;
    }
    int rank = (int)__popcll(before)
             + (int)__popcll(mine & ((1ull << lane) - 1ull));
    int sorted = __builtin_amdgcn_ds_permute(rank << 2, val);
    int val2 = (lane < total) ? (sorted & 0x1FFFF) : NN;   // pads -> zero row

    const int h = lane & 31;         // feature group 4h..4h+3 (dwords 2h,2h+1)
    const int hw = lane >> 5;        // 0: owns type tp, 1: owns type tp+1
    char* rowb = aggb + (size_t)(wid >> 7) * 32768 + (size_t)(wid & 127) * 256
               + (size_t)(((h >> 1) ^ (wid & 7)) << 4) + (h & 1) * 8;
    const size_t tstride = (size_t)nc * 256;
    unsigned msk = 0;

    #pragma unroll
    for (int tp = 0; tp < 7; tp += 2) {
        const int cA = ct[tp];
        const int cB = (tp + 1 < 7) ? ct[tp + 1] : 0;
        const int sA = st[tp];
        const int sB = (tp + 1 < 7) ? st[tp + 1] : 0;
        const int cM = hw ? cB : cA;         // my half's exact count (per-lane)
        const int sM = hw ? sB : sA;
        const int cMax = cA > cB ? cA : cB;  // WAVE-UNIFORM loop bound

        float a0 = 0.f, a1 = 0.f, a2 = 0.f, a3 = 0.f;
        for (int e = 0; e < cMax; e += 2) {  // uniform bound: all lanes loop
            int i0 = (sM + e) & 63;
            int i1 = (sM + e + 1) & 63;
            int r0 = __shfl(val2, i0);       // ALL 64 lanes active (required)
            int r1 = __shfl(val2, i1);
            int s0_ = (e < cM)     ? r0 : NN;     // pad -> zero row
            int s1_ = (e + 1 < cM) ? r1 : NN;
            uint2 v0 = *(const uint2*)(xb + (size_t)s0_ * 256 + h * 8);
            uint2 v1 = *(const uint2*)(xb + (size_t)s1_ * 256 + h * 8);
            a0 += __uint_as_float(v0.x << 16) + __uint_as_float(v1.x << 16);
            a1 += __uint_as_float(v0.x & 0xFFFF0000u) + __uint_as_float(v1.x & 0xFFFF0000u);
            a2 += __uint_as_float(v0.y << 16) + __uint_as_float(v1.y << 16);
            a3 += __uint_as_float(v0.y & 0xFFFF0000u) + __uint_as_float(v1.y & 0xFFFF0000u);
        }
        float sc = 1.0f / fmaxf((float)cM, 1.0f);   // mean folded pre-GEMM
        if (tp + hw < 7) {                   // half1 has no type when tp==6
            uint2 d;
            d.x = pack_bf16x2(a0 * sc, a1 * sc);
            d.y = pack_bf16x2(a2 * sc, a3 * sc);
            *(uint2*)(rowb + (size_t)(tp + hw) * tstride) = d;
        }
        msk |= (cA > 0) ? (1u << tp) : 0u;
        if (tp + 1 < 7) msk |= (cB > 0) ? (1u << (tp + 1)) : 0u;
    }
    if (live && lane == 0) bmask[n] = (unsigned char)msk;
}

// ------------------------------------------------------------------ gemm ----
// 512 threads = 8 waves; wave w=(wy,wx): rows wy*32..+31, cols wx*64..+63.
// 14 steps (7 types x 2 K-halves of 64). Single 32KB buffer -> 4 blocks/CU;
// all 782 blocks co-resident, staging overlaps across blocks.
__global__ __launch_bounds__(512) void gemm_k(
    const char* __restrict__ aggb, const char* __restrict__ WTb,
    const unsigned char* __restrict__ bmask, const float* __restrict__ bias,
    float* __restrict__ out, int c0, int nc)
{
    __shared__ char sA[128 * 128];   // 16 KB: 128 rows x 128B K-half
    __shared__ char sW[128 * 128];   // 16 KB
    int tid = threadIdx.x;
    int w = tid >> 6, lane = tid & 63;
    int wy = w >> 1, wx = w & 1;
    int n0 = c0 + blockIdx.x * 128;
    const size_t tstride = (size_t)nc * 256;
    const char* abase0 = aggb + (size_t)blockIdx.x * 32768;
    const int ro = (lane >> 3) * 256 + (lane & 7) * 16;  // 8 rows x 128B / 1KB chunk

    f32x4 acc[2][4];
    #pragma unroll
    for (int i = 0; i < 2; ++i)
        #pragma unroll
        for (int j = 0; j < 4; ++j) acc[i][j] = (f32x4)0.0f;

    for (int s = 0; s < 14; ++s) {
        int t = s >> 1, h = s & 1;
        __syncthreads();   // prev step's readers done before restage
        const char* ab = abase0 + (size_t)t * tstride + h * 128;
        const char* wb = WTb + (size_t)t * 32768 + h * 128;
        #pragma unroll
        for (int i = 0; i < 2; ++i) {            // A,W: 16 chunks x 1KB each
            int ch = w * 2 + i;
            __builtin_amdgcn_global_load_lds(
                (const __attribute__((address_space(1))) void*)(ab + ch * 2048 + ro),
                (__attribute__((address_space(3))) void*)(sA + ch * 1024), 16, 0, 0);
            __builtin_amdgcn_global_load_lds(
                (const __attribute__((address_space(1))) void*)(wb + ch * 2048 + ro),
                (__attribute__((address_space(3))) void*)(sW + ch * 1024), 16, 0, 0);
        }
        __syncthreads();   // compiler drains vmcnt before barrier

        #pragma unroll
        for (int cl = 0; cl < 2; ++cl) {
            int gsel = ((cl * 4 + (lane >> 4)) ^ (lane & 7)) << 4;
            bf16x8 A0 = *(const bf16x8*)(sA + (wy * 32 + (lane & 15)) * 128 + gsel);
            bf16x8 A1 = *(const bf16x8*)(sA + (wy * 32 + 16 + (lane & 15)) * 128 + gsel);
            #pragma unroll
            for (int nj = 0; nj < 4; ++nj) {
                bf16x8 B = *(const bf16x8*)(sW + (wx * 64 + nj * 16 + (lane & 15)) * 128 + gsel);
                acc[0][nj] = __builtin_amdgcn_mfma_f32_16x16x32_bf16(A0, B, acc[0][nj], 0, 0, 0);
                acc[1][nj] = __builtin_amdgcn_mfma_f32_16x16x32_bf16(A1, B, acc[1][nj], 0, 0, 0);
            }
        }
    }

    // epilogue: mean over types + per-type bias where the node has edges
    const float inv7 = 1.0f / (float)NT;
    #pragma unroll
    for (int mi = 0; mi < 2; ++mi) {
        #pragma unroll
        for (int v = 0; v < 4; ++v) {
            int n = n0 + wy * 32 + mi * 16 + (lane >> 4) * 4 + v;
            if (n >= NN) continue;
            unsigned mk = bmask[n];
            float add[4] = {0.f, 0.f, 0.f, 0.f};
            #pragma unroll
            for (int t = 0; t < NT; ++t) {
                if ((mk >> t) & 1u) {
                    #pragma unroll
                    for (int nj = 0; nj < 4; ++nj)
                        add[nj] += bias[(size_t)t * DD + wx * 64 + nj * 16 + (lane & 15)];
                }
            }
            #pragma unroll
            for (int nj = 0; nj < 4; ++nj)
                out[(size_t)n * DD + wx * 64 + nj * 16 + (lane & 15)]
                    = inv7 * (acc[mi][nj][v] + add[nj]);
        }
    }
}

// ---------------------------------------------------------------- launch ----
extern "C" void kernel_launch(void* const* d_in, const int* in_sizes, int n_in,
                              void* d_out, int out_size, void* d_ws, size_t ws_size,
                              hipStream_t stream) {
    const float* x  = (const float*)d_in[0];
    const int*   ei = (const int*)d_in[1];
    const float* W  = (const float*)d_in[2];
    const float* b  = (const float*)d_in[3];
    float* out = (float*)d_out;
    char* ws = (char*)d_ws;

    // fixed tables: ~52 MB; aggb 179.4 MB -> total ~231 MB (ws proven)
    size_t off = 0;
    char* xb     = ws + off; off += (size_t)(NN + 1) * 256;            // 25.6 MB
    char* WTb    = ws + off; off += (size_t)NT * 128 * 256;            // 224 KB
    int*  eslots = (int*)(ws + off); off += (size_t)NN * 64 * 4;       // 25.6 MB
    int*  cntT   = (int*)(ws + off); off += (size_t)NN * 4;            // 400 KB
    unsigned char* bmask = (unsigned char*)(ws + off); off += (size_t)NN; // 100 KB
    off = (off + 255) & ~(size_t)255;
    char* aggb   = ws + off;                                           // remainder

    size_t avail = (ws_size > off) ? (ws_size - off) : 0;
    int Nc = (int)(avail / ((size_t)NT * 256));
    Nc &= ~127;
    if (Nc < 128) Nc = 128;
    if (Nc > NROWS) Nc = NROWS;

    convx_k<<<(NN * DD / 8 + 255) / 256, 256, 0, stream>>>(x, (uint4*)xb);
    hipMemsetAsync(xb + (size_t)NN * 256, 0, 256, stream);   // zero pad row
    wconv_k<<<(NT * 128 + 3) / 4, 256, 0, stream>>>(W, WTb);
    hipMemsetAsync(cntT, 0, (size_t)NN * 4, stream);
    fill_k<<<dim3(NSLAB * NPART, NT), 256, 0, stream>>>(ei, cntT, eslots);

    for (int c0 = 0; c0 < NN; c0 += Nc) {
        int nc = (NROWS - c0 < Nc) ? (NROWS - c0) : Nc;   // multiple of 128
        agg_k<<<nc / 4, 256, 0, stream>>>(xb, cntT, eslots, aggb, bmask, c0, nc);
        gemm_k<<<nc / 128, 512, 0, stream>>>(aggb, WTb, bmask, b, out, c0, nc);
    }
}

// Round 19
// 258.769 us; speedup vs baseline: 1.8612x; 1.0008x over previous
//
#include <hip/hip_runtime.h>

// SwitchGNN split pipeline (R19 = R16 + A-to-VGPR / W-prestage gemm):
//  out = (1/7) * sum_t [ (segsum_t(x[src]) / max(cnt,1)) @ W_t + 1{cnt>0} b_t ]
// P0 convx_k: x -> bf16 rows (256B each); row NN is an all-zero pad row
// P1 wconv_k: W -> bf16, transposed [t][f][k], XOR-swizzled
// P2 fill_k : per-node 64-slot bucket (val = src|t<<17), XCD-partitioned
// P3 agg_k  : R16 proven (ballot sort, half-wave type split, b64 gathers)
// P4 gemm_k : A-fragments DIRECT global->VGPR (swizzled granule = contiguous
//             64B line; no LDS round-trip, no A-stage drain). W double-
//             buffered in LDS, staged one step AHEAD so its gll drain
//             happens at the NEXT step's barrier (a full step to complete).
//             One barrier/step; compiler's counted vmcnt covers A-loads.

constexpr int NN = 100000;
constexpr int NT = 7;
constexpr int NE = 250000;
constexpr int DD = 128;
constexpr int NROWS = ((NN + 127) / 128) * 128;   // 100096 padded rows
constexpr int NPART = 8;                          // dst partitions = XCDs
constexpr int PSIZE = (NN + NPART - 1) / NPART;   // 12500 nodes per partition
constexpr int EPB = 1024;                         // edges per fill block
constexpr int NSLAB = (NE + EPB - 1) / EPB;       // 245 slabs

typedef short bf16x8 __attribute__((ext_vector_type(8)));
typedef float f32x4 __attribute__((ext_vector_type(4)));
typedef int   i32x4 __attribute__((ext_vector_type(4)));
typedef float fltx4 __attribute__((ext_vector_type(4)));

__device__ __forceinline__ unsigned pack_bf16x2(float lo, float hi) {
    unsigned a = __float_as_uint(lo), b = __float_as_uint(hi);
    unsigned al = (a + 0x7FFFu + ((a >> 16) & 1u)) >> 16;          // RNE
    unsigned bh = (b + 0x7FFFu + ((b >> 16) & 1u)) & 0xFFFF0000u;
    return al | bh;
}

// ---------------------------------------------------------------- conv x ----
__global__ __launch_bounds__(256) void convx_k(
    const float* __restrict__ x, uint4* __restrict__ xb)
{
    int id = blockIdx.x * 256 + threadIdx.x;
    const fltx4* src = (const fltx4*)x;
    fltx4 v0 = __builtin_nontemporal_load(src + (size_t)id * 2);
    fltx4 v1 = __builtin_nontemporal_load(src + (size_t)id * 2 + 1);
    uint4 o;
    o.x = pack_bf16x2(v0[0], v0[1]);
    o.y = pack_bf16x2(v0[2], v0[3]);
    o.z = pack_bf16x2(v1[0], v1[1]);
    o.w = pack_bf16x2(v1[2], v1[3]);
    xb[id] = o;
}

// ---------------------------------------------------------------- W conv ----
__global__ __launch_bounds__(256) void wconv_k(
    const float* __restrict__ W, char* __restrict__ WTb)
{
    int wid = (blockIdx.x * 256 + threadIdx.x) >> 6;
    int lane = threadIdx.x & 63;
    int t = wid >> 7, f = wid & 127;
    if (t >= NT) return;
    const float* Wt = W + (size_t)t * DD * DD;
    float w0 = Wt[(size_t)(2 * lane) * DD + f];
    float w1 = Wt[(size_t)(2 * lane + 1) * DD + f];
    int gran = (lane >> 2) ^ (f & 7);
    *(unsigned*)(WTb + (size_t)t * 32768 + f * 256 + gran * 16 + (lane & 3) * 4)
        = pack_bf16x2(w0, w1);
}

// ------------------------------------------------------------------ fill ----
__global__ __launch_bounds__(256) void fill_k(
    const int* __restrict__ ei,      // [NT][2][NE]
    int* __restrict__ cntT,          // [NN], zeroed
    int* __restrict__ eslots)        // [NN][64]
{
    int part = blockIdx.x & (NPART - 1);
    int slab = blockIdx.x >> 3;
    int t = blockIdx.y;
    int e0 = slab * EPB + threadIdx.x * 4;
    if (e0 >= NE) return;
    const int* p = ei + (size_t)t * 2 * NE;
    i32x4 s4 = __builtin_nontemporal_load((const i32x4*)(p + e0));
    i32x4 d4 = __builtin_nontemporal_load((const i32x4*)(p + NE + e0));
    int lo = part * PSIZE;
    int hi = lo + PSIZE;
    int tv = t << 17;
    #pragma unroll
    for (int k = 0; k < 4; ++k) {
        int src = s4[k];
        int dst = d4[k];
        if (dst >= lo && dst < hi) {
            int pos = atomicAdd(cntT + dst, 1);
            if (pos < 64) eslots[(size_t)dst * 64 + pos] = src | tv;
        }
    }
}

// ------------------------------------------------------------- aggregate ----
// R16 proven. One wave per row; ballot counts + popc-rank + ds_permute sort;
// half-wave type split with b64 gathers; all shfls wave-uniform, all lanes.
__global__ __launch_bounds__(256) void agg_k(
    const char* __restrict__ xb,     // [NN+1][256B] bf16 rows (row NN = zeros)
    const int* __restrict__ cntT,    // [NN]
    const int* __restrict__ eslots,  // [NN][64]
    char* __restrict__ aggb,         // [NT][nc][256B], 128-row tiles, swizzled
    unsigned char* __restrict__ bmask, // [NN] per-type has-edges bits
    int c0, int nc)
{
    int wid = (blockIdx.x * 256 + threadIdx.x) >> 6;
    int lane = threadIdx.x & 63;
    if (wid >= nc) return;
    const int n = c0 + wid;
    const bool live = (n < NN);

    int total = live ? cntT[n] : 0;
    if (total > 64) total = 64;      // P(Poisson(17.5)>64) ~ 1e-19
    int val = (live && lane < total)
            ? __builtin_nontemporal_load(eslots + (size_t)n * 64 + lane) : 0;
    int mytype = (lane < total) ? ((val >> 17) & 7) : 7;

    unsigned long long bal[8];
    #pragma unroll
    for (int t = 0; t < 8; ++t) bal[t] = __ballot(mytype == t);
    int ct[7], st[7];
    {
        int s = 0;
        #pragma unroll
        for (int t = 0; t < 7; ++t) { st[t] = s; ct[t] = (int)__popcll(bal[t]); s += ct[t]; }
    }

    unsigned long long before = 0, mine = bal[7];
    #pragma unroll
    for (int t = 0; t < 7; ++t) {
        before |= (mytype > t) ? bal[t] : 0ull;
        mine = (mytype == t) ? bal[t] : mine;
    }
    int rank = (int)__popcll(before)
             + (int)__popcll(mine & ((1ull << lane) - 1ull));
    int sorted = __builtin_amdgcn_ds_permute(rank << 2, val);
    int val2 = (lane < total) ? (sorted & 0x1FFFF) : NN;   // pads -> zero row

    const int h = lane & 31;         // feature group 4h..4h+3 (dwords 2h,2h+1)
    const int hw = lane >> 5;        // 0: owns type tp, 1: owns type tp+1
    char* rowb = aggb + (size_t)(wid >> 7) * 32768 + (size_t)(wid & 127) * 256
               + (size_t)(((h >> 1) ^ (wid & 7)) << 4) + (h & 1) * 8;
    const size_t tstride = (size_t)nc * 256;
    unsigned msk = 0;

    #pragma unroll
    for (int tp = 0; tp < 7; tp += 2) {
        const int cA = ct[tp];
        const int cB = (tp + 1 < 7) ? ct[tp + 1] : 0;
        const int sA = st[tp];
        const int sB = (tp + 1 < 7) ? st[tp + 1] : 0;
        const int cM = hw ? cB : cA;         // my half's exact count (per-lane)
        const int sM = hw ? sB : sA;
        const int cMax = cA > cB ? cA : cB;  // WAVE-UNIFORM loop bound

        float a0 = 0.f, a1 = 0.f, a2 = 0.f, a3 = 0.f;
        for (int e = 0; e < cMax; e += 2) {  // uniform bound: all lanes loop
            int i0 = (sM + e) & 63;
            int i1 = (sM + e + 1) & 63;
            int r0 = __shfl(val2, i0);       // ALL 64 lanes active (required)
            int r1 = __shfl(val2, i1);
            int s0_ = (e < cM)     ? r0 : NN;     // pad -> zero row
            int s1_ = (e + 1 < cM) ? r1 : NN;
            uint2 v0 = *(const uint2*)(xb + (size_t)s0_ * 256 + h * 8);
            uint2 v1 = *(const uint2*)(xb + (size_t)s1_ * 256 + h * 8);
            a0 += __uint_as_float(v0.x << 16) + __uint_as_float(v1.x << 16);
            a1 += __uint_as_float(v0.x & 0xFFFF0000u) + __uint_as_float(v1.x & 0xFFFF0000u);
            a2 += __uint_as_float(v0.y << 16) + __uint_as_float(v1.y << 16);
            a3 += __uint_as_float(v0.y & 0xFFFF0000u) + __uint_as_float(v1.y & 0xFFFF0000u);
        }
        float sc = 1.0f / fmaxf((float)cM, 1.0f);   // mean folded pre-GEMM
        if (tp + hw < 7) {                   // half1 has no type when tp==6
            uint2 d;
            d.x = pack_bf16x2(a0 * sc, a1 * sc);
            d.y = pack_bf16x2(a2 * sc, a3 * sc);
            *(uint2*)(rowb + (size_t)(tp + hw) * tstride) = d;
        }
        msk |= (cA > 0) ? (1u << tp) : 0u;
        if (tp + 1 < 7) msk |= (cB > 0) ? (1u << (tp + 1)) : 0u;
    }
    if (live && lane == 0) bmask[n] = (unsigned char)msk;
}

// ------------------------------------------------------------------ gemm ----
// 512 threads = 8 waves; wave w=(wy,wx): rows wy*32..+31, cols wx*64..+63.
// K-loop over 7 types (BK=128). A-fragments read DIRECTLY from global
// (swizzled granule = contiguous 64B line per (row,cl)); W double-buffered
// in LDS, staged one step ahead. One barrier per step (top of loop).
__global__ __launch_bounds__(512) void gemm_k(
    const char* __restrict__ aggb, const char* __restrict__ WTb,
    const unsigned char* __restrict__ bmask, const float* __restrict__ bias,
    float* __restrict__ out, int c0, int nc)
{
    __shared__ char sW[2][128 * 256];   // 2 x 32 KB double-buffered W tile
    int tid = threadIdx.x;
    int w = tid >> 6, lane = tid & 63;
    int wy = w >> 1, wx = w & 1;
    int n0 = c0 + blockIdx.x * 128;
    const size_t tstride = (size_t)nc * 256;
    const char* abase = aggb + (size_t)blockIdx.x * 32768;

    // stage W tile for type t into buffer buf (32 chunks x 1KB, 4 per wave)
    auto stageW = [&](int buf, int t) {
        const char* wsrc = WTb + (size_t)t * 32768;
        #pragma unroll
        for (int i = 0; i < 4; ++i) {
            int ch = w * 4 + i;
            __builtin_amdgcn_global_load_lds(
                (const __attribute__((address_space(1))) void*)(wsrc + ch * 1024 + lane * 16),
                (__attribute__((address_space(3))) void*)(&sW[buf][ch * 1024]), 16, 0, 0);
        }
    };

    f32x4 acc[2][4];
    #pragma unroll
    for (int i = 0; i < 2; ++i)
        #pragma unroll
        for (int j = 0; j < 4; ++j) acc[i][j] = (f32x4)0.0f;

    stageW(0, 0);
    for (int t = 0; t < NT; ++t) {
        // barrier: (a) drains this wave's W(t) gll (compiler emits vmcnt(0))
        // and makes it LDS-visible to all waves; (b) all waves done reading
        // sW[(t-1)&1] before it is restaged below.
        __syncthreads();
        if (t + 1 < NT) stageW((t + 1) & 1, t + 1);

        // A-fragments: direct global loads (each a contiguous 64B-line 16B slice)
        const char* At = abase + (size_t)t * tstride;
        bf16x8 A0[4], A1[4];
        #pragma unroll
        for (int cl = 0; cl < 4; ++cl) {
            int gsel = ((cl * 4 + (lane >> 4)) ^ (lane & 7)) << 4;
            const char* ar = At + (size_t)(wy * 32 + (lane & 15)) * 256 + gsel;
            A0[cl] = *(const bf16x8*)(ar);
            A1[cl] = *(const bf16x8*)(ar + 16 * 256);
        }

        const char* Ws = sW[t & 1];
        #pragma unroll
        for (int cl = 0; cl < 4; ++cl) {
            int gsel = ((cl * 4 + (lane >> 4)) ^ (lane & 7)) << 4;
            #pragma unroll
            for (int nj = 0; nj < 4; ++nj) {
                bf16x8 B = *(const bf16x8*)(Ws + (wx * 64 + nj * 16 + (lane & 15)) * 256 + gsel);
                acc[0][nj] = __builtin_amdgcn_mfma_f32_16x16x32_bf16(A0[cl], B, acc[0][nj], 0, 0, 0);
                acc[1][nj] = __builtin_amdgcn_mfma_f32_16x16x32_bf16(A1[cl], B, acc[1][nj], 0, 0, 0);
            }
        }
    }

    // epilogue: mean over types + per-type bias where the node has edges
    const float inv7 = 1.0f / (float)NT;
    #pragma unroll
    for (int mi = 0; mi < 2; ++mi) {
        #pragma unroll
        for (int v = 0; v < 4; ++v) {
            int n = n0 + wy * 32 + mi * 16 + (lane >> 4) * 4 + v;
            if (n >= NN) continue;
            unsigned mk = bmask[n];
            float add[4] = {0.f, 0.f, 0.f, 0.f};
            #pragma unroll
            for (int t = 0; t < NT; ++t) {
                if ((mk >> t) & 1u) {
                    #pragma unroll
                    for (int nj = 0; nj < 4; ++nj)
                        add[nj] += bias[(size_t)t * DD + wx * 64 + nj * 16 + (lane & 15)];
                }
            }
            #pragma unroll
            for (int nj = 0; nj < 4; ++nj)
                out[(size_t)n * DD + wx * 64 + nj * 16 + (lane & 15)]
                    = inv7 * (acc[mi][nj][v] + add[nj]);
        }
    }
}

// ---------------------------------------------------------------- launch ----
extern "C" void kernel_launch(void* const* d_in, const int* in_sizes, int n_in,
                              void* d_out, int out_size, void* d_ws, size_t ws_size,
                              hipStream_t stream) {
    const float* x  = (const float*)d_in[0];
    const int*   ei = (const int*)d_in[1];
    const float* W  = (const float*)d_in[2];
    const float* b  = (const float*)d_in[3];
    float* out = (float*)d_out;
    char* ws = (char*)d_ws;

    // fixed tables: ~52 MB; aggb 179.4 MB -> total ~231 MB (ws proven)
    size_t off = 0;
    char* xb     = ws + off; off += (size_t)(NN + 1) * 256;            // 25.6 MB
    char* WTb    = ws + off; off += (size_t)NT * 128 * 256;            // 224 KB
    int*  eslots = (int*)(ws + off); off += (size_t)NN * 64 * 4;       // 25.6 MB
    int*  cntT   = (int*)(ws + off); off += (size_t)NN * 4;            // 400 KB
    unsigned char* bmask = (unsigned char*)(ws + off); off += (size_t)NN; // 100 KB
    off = (off + 255) & ~(size_t)255;
    char* aggb   = ws + off;                                           // remainder

    size_t avail = (ws_size > off) ? (ws_size - off) : 0;
    int Nc = (int)(avail / ((size_t)NT * 256));
    Nc &= ~127;
    if (Nc < 128) Nc = 128;
    if (Nc > NROWS) Nc = NROWS;

    convx_k<<<(NN * DD / 8 + 255) / 256, 256, 0, stream>>>(x, (uint4*)xb);
    hipMemsetAsync(xb + (size_t)NN * 256, 0, 256, stream);   // zero pad row
    wconv_k<<<(NT * 128 + 3) / 4, 256, 0, stream>>>(W, WTb);
    hipMemsetAsync(cntT, 0, (size_t)NN * 4, stream);
    fill_k<<<dim3(NSLAB * NPART, NT), 256, 0, stream>>>(ei, cntT, eslots);

    for (int c0 = 0; c0 < NN; c0 += Nc) {
        int nc = (NROWS - c0 < Nc) ? (NROWS - c0) : Nc;   // multiple of 128
        agg_k<<<nc / 4, 256, 0, stream>>>(xb, cntT, eslots, aggb, bmask, c0, nc);
        gemm_k<<<nc / 128, 512, 0, stream>>>(aggb, WTb, bmask, b, out, c0, nc);
    }
}

// Round 20
// 257.642 us; speedup vs baseline: 1.8693x; 1.0044x over previous
//
#include <hip/hip_runtime.h>

// SwitchGNN split pipeline (R19 = R16 + A-to-VGPR / W-prestage gemm):
//  out = (1/7) * sum_t [ (segsum_t(x[src]) / max(cnt,1)) @ W_t + 1{cnt>0} b_t ]
// P0 convx_k: x -> bf16 rows (256B each); row NN is an all-zero pad row
// P1 wconv_k: W -> bf16, transposed [t][f][k], XOR-swizzled
// P2 fill_k : per-node 64-slot bucket (val = src|t<<17), XCD-partitioned
// P3 agg_k  : R16 proven (ballot sort, half-wave type split, b64 gathers)
// P4 gemm_k : A-fragments DIRECT global->VGPR (swizzled granule = contiguous
//             64B line; no LDS round-trip, no A-stage drain). W double-
//             buffered in LDS, staged one step AHEAD so its gll drain
//             happens at the NEXT step's barrier (a full step to complete).
//             One barrier/step; compiler's counted vmcnt covers A-loads.

constexpr int NN = 100000;
constexpr int NT = 7;
constexpr int NE = 250000;
constexpr int DD = 128;
constexpr int NROWS = ((NN + 127) / 128) * 128;   // 100096 padded rows
constexpr int NPART = 8;                          // dst partitions = XCDs
constexpr int PSIZE = (NN + NPART - 1) / NPART;   // 12500 nodes per partition
constexpr int EPB = 1024;                         // edges per fill block
constexpr int NSLAB = (NE + EPB - 1) / EPB;       // 245 slabs

typedef short bf16x8 __attribute__((ext_vector_type(8)));
typedef float f32x4 __attribute__((ext_vector_type(4)));
typedef int   i32x4 __attribute__((ext_vector_type(4)));
typedef float fltx4 __attribute__((ext_vector_type(4)));

__device__ __forceinline__ unsigned pack_bf16x2(float lo, float hi) {
    unsigned a = __float_as_uint(lo), b = __float_as_uint(hi);
    unsigned al = (a + 0x7FFFu + ((a >> 16) & 1u)) >> 16;          // RNE
    unsigned bh = (b + 0x7FFFu + ((b >> 16) & 1u)) & 0xFFFF0000u;
    return al | bh;
}

// ---------------------------------------------------------------- conv x ----
__global__ __launch_bounds__(256) void convx_k(
    const float* __restrict__ x, uint4* __restrict__ xb)
{
    int id = blockIdx.x * 256 + threadIdx.x;
    const fltx4* src = (const fltx4*)x;
    fltx4 v0 = __builtin_nontemporal_load(src + (size_t)id * 2);
    fltx4 v1 = __builtin_nontemporal_load(src + (size_t)id * 2 + 1);
    uint4 o;
    o.x = pack_bf16x2(v0[0], v0[1]);
    o.y = pack_bf16x2(v0[2], v0[3]);
    o.z = pack_bf16x2(v1[0], v1[1]);
    o.w = pack_bf16x2(v1[2], v1[3]);
    xb[id] = o;
}

// ---------------------------------------------------------------- W conv ----
__global__ __launch_bounds__(256) void wconv_k(
    const float* __restrict__ W, char* __restrict__ WTb)
{
    int wid = (blockIdx.x * 256 + threadIdx.x) >> 6;
    int lane = threadIdx.x & 63;
    int t = wid >> 7, f = wid & 127;
    if (t >= NT) return;
    const float* Wt = W + (size_t)t * DD * DD;
    float w0 = Wt[(size_t)(2 * lane) * DD + f];
    float w1 = Wt[(size_t)(2 * lane + 1) * DD + f];
    int gran = (lane >> 2) ^ (f & 7);
    *(unsigned*)(WTb + (size_t)t * 32768 + f * 256 + gran * 16 + (lane & 3) * 4)
        = pack_bf16x2(w0, w1);
}

// ------------------------------------------------------------------ fill ----
__global__ __launch_bounds__(256) void fill_k(
    const int* __restrict__ ei,      // [NT][2][NE]
    int* __restrict__ cntT,          // [NN], zeroed
    int* __restrict__ eslots)        // [NN][64]
{
    int part = blockIdx.x & (NPART - 1);
    int slab = blockIdx.x >> 3;
    int t = blockIdx.y;
    int e0 = slab * EPB + threadIdx.x * 4;
    if (e0 >= NE) return;
    const int* p = ei + (size_t)t * 2 * NE;
    i32x4 s4 = __builtin_nontemporal_load((const i32x4*)(p + e0));
    i32x4 d4 = __builtin_nontemporal_load((const i32x4*)(p + NE + e0));
    int lo = part * PSIZE;
    int hi = lo + PSIZE;
    int tv = t << 17;
    #pragma unroll
    for (int k = 0; k < 4; ++k) {
        int src = s4[k];
        int dst = d4[k];
        if (dst >= lo && dst < hi) {
            int pos = atomicAdd(cntT + dst, 1);
            if (pos < 64) eslots[(size_t)dst * 64 + pos] = src | tv;
        }
    }
}

// ------------------------------------------------------------- aggregate ----
// R16 proven. One wave per row; ballot counts + popc-rank + ds_permute sort;
// half-wave type split with b64 gathers; all shfls wave-uniform, all lanes.
__global__ __launch_bounds__(256) void agg_k(
    const char* __restrict__ xb,     // [NN+1][256B] bf16 rows (row NN = zeros)
    const int* __restrict__ cntT,    // [NN]
    const int* __restrict__ eslots,  // [NN][64]
    char* __restrict__ aggb,         // [NT][nc][256B], 128-row tiles, swizzled
    unsigned char* __restrict__ bmask, // [NN] per-type has-edges bits
    int c0, int nc)
{
    int wid = (blockIdx.x * 256 + threadIdx.x) >> 6;
    int lane = threadIdx.x & 63;
    if (wid >= nc) return;
    const int n = c0 + wid;
    const bool live = (n < NN);

    int total = live ? cntT[n] : 0;
    if (total > 64) total = 64;      // P(Poisson(17.5)>64) ~ 1e-19
    int val = (live && lane < total)
            ? __builtin_nontemporal_load(eslots + (size_t)n * 64 + lane) : 0;
    int mytype = (lane < total) ? ((val >> 17) & 7) : 7;

    unsigned long long bal[8];
    #pragma unroll
    for (int t = 0; t < 8; ++t) bal[t] = __ballot(mytype == t);
    int ct[7], st[7];
    {
        int s = 0;
        #pragma unroll
        for (int t = 0; t < 7; ++t) { st[t] = s; ct[t] = (int)__popcll(bal[t]); s += ct[t]; }
    }

    unsigned long long before = 0, mine = bal[7];
    #pragma unroll
    for (int t = 0; t < 7; ++t) {
        before |= (mytype > t) ? bal[t] : 0ull;
        mine = (mytype == t) ? bal[t] : mine;
    }
    int rank = (int)__popcll(before)
             + (int)__popcll(mine & ((1ull << lane) - 1ull));
    int sorted = __builtin_amdgcn_ds_permute(rank << 2, val);
    int val2 = (lane < total) ? (sorted & 0x1FFFF) : NN;   // pads -> zero row

    const int h = lane & 31;         // feature group 4h..4h+3 (dwords 2h,2h+1)
    const int hw = lane >> 5;        // 0: owns type tp, 1: owns type tp+1
    char* rowb = aggb + (size_t)(wid >> 7) * 32768 + (size_t)(wid & 127) * 256
               + (size_t)(((h >> 1) ^ (wid & 7)) << 4) + (h & 1) * 8;
    const size_t tstride = (size_t)nc * 256;
    unsigned msk = 0;

    #pragma unroll
    for (int tp = 0; tp < 7; tp += 2) {
        const int cA = ct[tp];
        const int cB = (tp + 1 < 7) ? ct[tp + 1] : 0;
        const int sA = st[tp];
        const int sB = (tp + 1 < 7) ? st[tp + 1] : 0;
        const int cM = hw ? cB : cA;         // my half's exact count (per-lane)
        const int sM = hw ? sB : sA;
        const int cMax = cA > cB ? cA : cB;  // WAVE-UNIFORM loop bound

        float a0 = 0.f, a1 = 0.f, a2 = 0.f, a3 = 0.f;
        for (int e = 0; e < cMax; e += 2) {  // uniform bound: all lanes loop
            int i0 = (sM + e) & 63;
            int i1 = (sM + e + 1) & 63;
            int r0 = __shfl(val2, i0);       // ALL 64 lanes active (required)
            int r1 = __shfl(val2, i1);
            int s0_ = (e < cM)     ? r0 : NN;     // pad -> zero row
            int s1_ = (e + 1 < cM) ? r1 : NN;
            uint2 v0 = *(const uint2*)(xb + (size_t)s0_ * 256 + h * 8);
            uint2 v1 = *(const uint2*)(xb + (size_t)s1_ * 256 + h * 8);
            a0 += __uint_as_float(v0.x << 16) + __uint_as_float(v1.x << 16);
            a1 += __uint_as_float(v0.x & 0xFFFF0000u) + __uint_as_float(v1.x & 0xFFFF0000u);
            a2 += __uint_as_float(v0.y << 16) + __uint_as_float(v1.y << 16);
            a3 += __uint_as_float(v0.y & 0xFFFF0000u) + __uint_as_float(v1.y & 0xFFFF0000u);
        }
        float sc = 1.0f / fmaxf((float)cM, 1.0f);   // mean folded pre-GEMM
        if (tp + hw < 7) {                   // half1 has no type when tp==6
            uint2 d;
            d.x = pack_bf16x2(a0 * sc, a1 * sc);
            d.y = pack_bf16x2(a2 * sc, a3 * sc);
            *(uint2*)(rowb + (size_t)(tp + hw) * tstride) = d;
        }
        msk |= (cA > 0) ? (1u << tp) : 0u;
        if (tp + 1 < 7) msk |= (cB > 0) ? (1u << (tp + 1)) : 0u;
    }
    if (live && lane == 0) bmask[n] = (unsigned char)msk;
}

// ------------------------------------------------------------------ gemm ----
// 512 threads = 8 waves; wave w=(wy,wx): rows wy*32..+31, cols wx*64..+63.
// K-loop over 7 types (BK=128). A-fragments read DIRECTLY from global
// (swizzled granule = contiguous 64B line per (row,cl)); W double-buffered
// in LDS, staged one step ahead. One barrier per step (top of loop).
__global__ __launch_bounds__(512) void gemm_k(
    const char* __restrict__ aggb, const char* __restrict__ WTb,
    const unsigned char* __restrict__ bmask, const float* __restrict__ bias,
    float* __restrict__ out, int c0, int nc)
{
    __shared__ char sW[2][128 * 256];   // 2 x 32 KB double-buffered W tile
    int tid = threadIdx.x;
    int w = tid >> 6, lane = tid & 63;
    int wy = w >> 1, wx = w & 1;
    int n0 = c0 + blockIdx.x * 128;
    const size_t tstride = (size_t)nc * 256;
    const char* abase = aggb + (size_t)blockIdx.x * 32768;

    // stage W tile for type t into buffer buf (32 chunks x 1KB, 4 per wave)
    auto stageW = [&](int buf, int t) {
        const char* wsrc = WTb + (size_t)t * 32768;
        #pragma unroll
        for (int i = 0; i < 4; ++i) {
            int ch = w * 4 + i;
            __builtin_amdgcn_global_load_lds(
                (const __attribute__((address_space(1))) void*)(wsrc + ch * 1024 + lane * 16),
                (__attribute__((address_space(3))) void*)(&sW[buf][ch * 1024]), 16, 0, 0);
        }
    };

    f32x4 acc[2][4];
    #pragma unroll
    for (int i = 0; i < 2; ++i)
        #pragma unroll
        for (int j = 0; j < 4; ++j) acc[i][j] = (f32x4)0.0f;

    stageW(0, 0);
    for (int t = 0; t < NT; ++t) {
        // barrier: (a) drains this wave's W(t) gll (compiler emits vmcnt(0))
        // and makes it LDS-visible to all waves; (b) all waves done reading
        // sW[(t-1)&1] before it is restaged below.
        __syncthreads();
        if (t + 1 < NT) stageW((t + 1) & 1, t + 1);

        // A-fragments: direct global loads (each a contiguous 64B-line 16B slice)
        const char* At = abase + (size_t)t * tstride;
        bf16x8 A0[4], A1[4];
        #pragma unroll
        for (int cl = 0; cl < 4; ++cl) {
            int gsel = ((cl * 4 + (lane >> 4)) ^ (lane & 7)) << 4;
            const char* ar = At + (size_t)(wy * 32 + (lane & 15)) * 256 + gsel;
            A0[cl] = *(const bf16x8*)(ar);
            A1[cl] = *(const bf16x8*)(ar + 16 * 256);
        }

        const char* Ws = sW[t & 1];
        #pragma unroll
        for (int cl = 0; cl < 4; ++cl) {
            int gsel = ((cl * 4 + (lane >> 4)) ^ (lane & 7)) << 4;
            #pragma unroll
            for (int nj = 0; nj < 4; ++nj) {
                bf16x8 B = *(const bf16x8*)(Ws + (wx * 64 + nj * 16 + (lane & 15)) * 256 + gsel);
                acc[0][nj] = __builtin_amdgcn_mfma_f32_16x16x32_bf16(A0[cl], B, acc[0][nj], 0, 0, 0);
                acc[1][nj] = __builtin_amdgcn_mfma_f32_16x16x32_bf16(A1[cl], B, acc[1][nj], 0, 0, 0);
            }
        }
    }

    // epilogue: mean over types + per-type bias where the node has edges
    const float inv7 = 1.0f / (float)NT;
    #pragma unroll
    for (int mi = 0; mi < 2; ++mi) {
        #pragma unroll
        for (int v = 0; v < 4; ++v) {
            int n = n0 + wy * 32 + mi * 16 + (lane >> 4) * 4 + v;
            if (n >= NN) continue;
            unsigned mk = bmask[n];
            float add[4] = {0.f, 0.f, 0.f, 0.f};
            #pragma unroll
            for (int t = 0; t < NT; ++t) {
                if ((mk >> t) & 1u) {
                    #pragma unroll
                    for (int nj = 0; nj < 4; ++nj)
                        add[nj] += bias[(size_t)t * DD + wx * 64 + nj * 16 + (lane & 15)];
                }
            }
            #pragma unroll
            for (int nj = 0; nj < 4; ++nj)
                out[(size_t)n * DD + wx * 64 + nj * 16 + (lane & 15)]
                    = inv7 * (acc[mi][nj][v] + add[nj]);
        }
    }
}

// ---------------------------------------------------------------- launch ----
extern "C" void kernel_launch(void* const* d_in, const int* in_sizes, int n_in,
                              void* d_out, int out_size, void* d_ws, size_t ws_size,
                              hipStream_t stream) {
    const float* x  = (const float*)d_in[0];
    const int*   ei = (const int*)d_in[1];
    const float* W  = (const float*)d_in[2];
    const float* b  = (const float*)d_in[3];
    float* out = (float*)d_out;
    char* ws = (char*)d_ws;

    // fixed tables: ~52 MB; aggb 179.4 MB -> total ~231 MB (ws proven)
    size_t off = 0;
    char* xb     = ws + off; off += (size_t)(NN + 1) * 256;            // 25.6 MB
    char* WTb    = ws + off; off += (size_t)NT * 128 * 256;            // 224 KB
    int*  eslots = (int*)(ws + off); off += (size_t)NN * 64 * 4;       // 25.6 MB
    int*  cntT   = (int*)(ws + off); off += (size_t)NN * 4;            // 400 KB
    unsigned char* bmask = (unsigned char*)(ws + off); off += (size_t)NN; // 100 KB
    off = (off + 255) & ~(size_t)255;
    char* aggb   = ws + off;                                           // remainder

    size_t avail = (ws_size > off) ? (ws_size - off) : 0;
    int Nc = (int)(avail / ((size_t)NT * 256));
    Nc &= ~127;
    if (Nc < 128) Nc = 128;
    if (Nc > NROWS) Nc = NROWS;

    convx_k<<<(NN * DD / 8 + 255) / 256, 256, 0, stream>>>(x, (uint4*)xb);
    hipMemsetAsync(xb + (size_t)NN * 256, 0, 256, stream);   // zero pad row
    wconv_k<<<(NT * 128 + 3) / 4, 256, 0, stream>>>(W, WTb);
    hipMemsetAsync(cntT, 0, (size_t)NN * 4, stream);
    fill_k<<<dim3(NSLAB * NPART, NT), 256, 0, stream>>>(ei, cntT, eslots);

    for (int c0 = 0; c0 < NN; c0 += Nc) {
        int nc = (NROWS - c0 < Nc) ? (NROWS - c0) : Nc;   // multiple of 128
        agg_k<<<nc / 4, 256, 0, stream>>>(xb, cntT, eslots, aggb, bmask, c0, nc);
        gemm_k<<<nc / 128, 512, 0, stream>>>(aggb, WTb, bmask, b, out, c0, nc);
    }
}